// Round 6
// baseline (49.843 us; speedup 1.0000x reference)
//
#include <hip/hip_runtime.h>

#define BSZ 8
#define SEQ 512
#define HID 768
#define N1 128
#define N2 24
#define HS 64
#define HEADS 12
#define INFV 10000.0f

typedef __attribute__((ext_vector_type(8))) short s8b;     // 8 bf16 (4 VGPR)
typedef __attribute__((ext_vector_type(4))) float f32x4;   // MFMA acc

__device__ __forceinline__ unsigned short f2bf(float f) {
    union { float f; unsigned int u; } c; c.f = f;
    unsigned int u = c.u;
    u += 0x7FFFu + ((u >> 16) & 1u);   // RNE
    return (unsigned short)(u >> 16);
}

// k0: 129 blocks x 128 thr.
//  blocks 0-95:  W1T[c][k] = bf16(W1[k][c])     (128 x 768 bf16)
//  block  96:    W2T[c][k] = W2[k][c]           (24 x 128 f32)
//  blocks 97-128: sincos table sct[m*32+j] = (sin, cos)(m * 10000^(-j/32))
__global__ __launch_bounds__(128) void k0_prep(
    const float* __restrict__ W1, const float* __restrict__ W2,
    unsigned short* __restrict__ W1T, float* __restrict__ W2T,
    float2* __restrict__ sct)
{
    const int tid = threadIdx.x;
    const int bid = blockIdx.x;
    if (bid < 96) {
        const int c = tid;
        const int k0 = bid * 8;
        unsigned short v[8];
#pragma unroll
        for (int i = 0; i < 8; ++i)
            v[i] = f2bf(W1[(size_t)(k0 + i) * N1 + c]);
        unsigned short* dst = W1T + (size_t)c * HID + k0;
#pragma unroll
        for (int i = 0; i < 8; ++i) dst[i] = v[i];
    } else if (bid == 96) {
#pragma unroll
        for (int c = 0; c < N2; ++c)
            W2T[c * N1 + tid] = W2[tid * N2 + c];
    } else {
        const float C = 0.4152410118609203f;      // log2(10000)/32
        int e0 = (bid - 97) * 512 + tid * 4;
#pragma unroll
        for (int u = 0; u < 4; ++u) {
            int e = e0 + u;
            int m = e >> 5, j = e & 31;
            float ang = (float)m * exp2f(-(float)j * C);
            float sv, cv;
            sincosf(ang, &sv, &cv);
            sct[e] = make_float2(sv, cv);
        }
    }
}

// k1: 512 blocks x 512 thr. Block = 16 rows x 64 cols (col-half ch = bid&1).
// 8 waves = 4 col-tiles x 2 K-halves; bf16 MFMA, LDS partial reduce.
// Epilogue: table-RoPE -> qw + kwT, bias partial (x-half @ W2T) -> bP[ch].
__global__ __launch_bounds__(512, 4) void k1_proj(
    const float* __restrict__ inp, const unsigned short* __restrict__ W1T,
    const float* __restrict__ b1, const float* __restrict__ W2T,
    const float* __restrict__ b2, const float2* __restrict__ sct,
    float* __restrict__ qw, float* __restrict__ kwT,
    float* __restrict__ bP0, float* __restrict__ bP1)
{
    __shared__ unsigned short aF[96 * 16 * 8];   // 24 KB: A bf16 frag layout
    __shared__ float ps[16][64];                 // 4 KB: K-half-1 partials
    __shared__ float xs[16][72];                 // x tile (pad 8 -> 16B-aligned rows)
    __shared__ float kT[32][17];                 // kwT transpose staging

    const int tid = threadIdx.x;
    const int rt = blockIdx.x >> 1;
    const int ch = blockIdx.x & 1;               // col half
    const int row0 = rt * 16;
    const int b = row0 >> 9;
    const int m0 = row0 & 511;

    {   // stage inp (fp32 -> bf16 fragment layout): 3072 float4, 6 per thread
        const float4* src = (const float4*)(inp + (size_t)row0 * HID);
#pragma unroll
        for (int i = 0; i < 6; ++i) {
            int f4 = tid + i * 512;        // 0..3071
            int r = f4 / 192;              // row 0..15
            int c4 = f4 % 192;             // float4 idx in row; k = c4*4
            float4 v = src[f4];
            int chunk = c4 >> 1;           // k/8
            int half = c4 & 1;
            ushort4 w;
            w.x = f2bf(v.x); w.y = f2bf(v.y); w.z = f2bf(v.z); w.w = f2bf(v.w);
            *(ushort4*)&aF[(chunk * 16 + r) * 8 + half * 4] = w;
        }
    }
    __syncthreads();

    const int wv = tid >> 6;
    const int ln = tid & 63;
    const int lr = ln & 15;        // A row / B col within tile
    const int lg = ln >> 4;        // k-group
    const int w3 = wv & 3;         // col tile
    const int kh = wv >> 2;        // K half
    const int cg = ch * 64 + w3 * 16 + lr;   // global x-col

    const s8b* bp = (const s8b*)W1T + ((size_t)cg * 96 + kh * 48 + lg);

    f32x4 acc = {0.f, 0.f, 0.f, 0.f};
#pragma unroll
    for (int kc = 0; kc < 12; ++kc) {
        s8b a = *(const s8b*)&aF[(((kh * 12 + kc) * 4 + lg) * 16 + lr) * 8];
        acc = __builtin_amdgcn_mfma_f32_16x16x32_bf16(a, bp[kc * 4], acc, 0, 0, 0);
    }

    if (kh == 1) {
#pragma unroll
        for (int g = 0; g < 4; ++g) ps[lg * 4 + g][w3 * 16 + lr] = acc[g];
    }
    __syncthreads();
    if (kh == 0) {   // merge halves + b1 -> xs (local col = w3*16+lr)
        float b1v = b1[cg];
#pragma unroll
        for (int g = 0; g < 4; ++g)
            xs[lg * 4 + g][w3 * 16 + lr] = acc[g] + ps[lg * 4 + g][w3 * 16 + lr] + b1v;
    }
    __syncthreads();

    // bias partial: bP[ch][(b,c,m)] = (x_half . W2T[c]  [+ b2 if ch==0]) * 0.5
    if (tid < 16 * N2) {
        int r = tid / N2, c = tid - r * N2;
        const float* xr = &xs[r][0];
        const float* wr = W2T + c * N1 + ch * 64;
        float dot = (ch == 0) ? b2[c] : 0.0f;
#pragma unroll
        for (int k4 = 0; k4 < 16; ++k4) {
            float4 xv = *(const float4*)&xr[k4 * 4];
            float4 wv2 = *(const float4*)&wr[k4 * 4];
            dot = fmaf(xv.x, wv2.x, dot); dot = fmaf(xv.y, wv2.y, dot);
            dot = fmaf(xv.z, wv2.z, dot); dot = fmaf(xv.w, wv2.w, dot);
        }
        float* bP = ch ? bP1 : bP0;
        bP[(size_t)(b * N2 + c) * SEQ + m0 + r] = dot * 0.5f;
    }

    if (tid < 256) {   // RoPE: 16 rows x 16 local pairs (j = ch*16 + jj)
        const int r = tid >> 4, jj = tid & 15;
        const int j = ch * 16 + jj;
        const int m = m0 + r;
        float2 sc = sct[m * 32 + j];
        float4 xv = *(const float4*)&xs[r][4 * jj];
        float rq0 = xv.x * sc.y - xv.z * sc.x;    // q pair = x[4j], x[4j+2]
        float rq1 = xv.x * sc.x + xv.z * sc.y;
        float rk0 = xv.y * sc.y - xv.w * sc.x;    // k pair = x[4j+1], x[4j+3]
        float rk1 = xv.y * sc.x + xv.w * sc.y;
        *(float2*)(qw + (size_t)(b * SEQ + m) * HS + 2 * j) = make_float2(rq0, rq1);
        kT[2 * jj][r]     = rk0;
        kT[2 * jj + 1][r] = rk1;
    }
    __syncthreads();

    if (tid < 256) {   // kwT writeout: 32 local d-rows x 8 m-pairs
        int dl = tid >> 3, q = tid & 7;
        float2 v = *(const float2*)&kT[dl][2 * q];
        *(float2*)(kwT + (size_t)(b * HS + ch * 32 + dl) * SEQ + m0 + 2 * q) = v;
    }
}

// k2: per block = (b, 8 m-rows) x 512 n. 256 threads, 2 n's each -> float2 stores.
__global__ __launch_bounds__(256) void k2_out(
    const float* __restrict__ qw, const float* __restrict__ kwT,
    const float* __restrict__ bP0, const float* __restrict__ bP1,
    const int* __restrict__ am, float* __restrict__ out)
{
    __shared__ float q_lds[8][HS];
    __shared__ float bo[8][HEADS];
    __shared__ int amm[8];

    const int tid = threadIdx.x;
    const int b = blockIdx.x >> 6;
    const int m0 = (blockIdx.x & 63) * 8;

#pragma unroll
    for (int i = 0; i < 2; ++i) {
        int idx = tid + i * 256;
        q_lds[idx >> 6][idx & 63] = qw[(size_t)(b * SEQ + m0) * HS + idx];
    }
    if (tid < 96) {
        int r = tid / 12, h = tid - r * 12;
        size_t ix = (size_t)(b * N2 + 2 * h + 1) * SEQ + m0 + r;
        bo[r][h] = bP0[ix] + bP1[ix];
    }
    if (tid < 8) amm[tid] = am[b * SEQ + m0 + tid];
    __syncthreads();

    const int n0 = tid * 2;
    float qk0[8] = {0, 0, 0, 0, 0, 0, 0, 0};
    float qk1[8] = {0, 0, 0, 0, 0, 0, 0, 0};

#pragma unroll
    for (int dc = 0; dc < 2; ++dc) {
        float2 kn[32];
#pragma unroll
        for (int d = 0; d < 32; ++d)
            kn[d] = *(const float2*)&kwT[(size_t)(b * HS + dc * 32 + d) * SEQ + n0];
#pragma unroll
        for (int r = 0; r < 8; ++r) {
#pragma unroll
            for (int d4 = 0; d4 < 8; ++d4) {
                float4 qv = *(const float4*)&q_lds[r][dc * 32 + d4 * 4];
                qk0[r] = fmaf(qv.x, kn[d4 * 4 + 0].x, qk0[r]);
                qk0[r] = fmaf(qv.y, kn[d4 * 4 + 1].x, qk0[r]);
                qk0[r] = fmaf(qv.z, kn[d4 * 4 + 2].x, qk0[r]);
                qk0[r] = fmaf(qv.w, kn[d4 * 4 + 3].x, qk0[r]);
                qk1[r] = fmaf(qv.x, kn[d4 * 4 + 0].y, qk1[r]);
                qk1[r] = fmaf(qv.y, kn[d4 * 4 + 1].y, qk1[r]);
                qk1[r] = fmaf(qv.z, kn[d4 * 4 + 2].y, qk1[r]);
                qk1[r] = fmaf(qv.w, kn[d4 * 4 + 3].y, qk1[r]);
            }
        }
    }

    const int amn0 = am[b * SEQ + n0];
    const int amn1 = am[b * SEQ + n0 + 1];
    float pen0[8], pen1[8];
    float2 mo[8];
#pragma unroll
    for (int r = 0; r < 8; ++r) {
        int m = m0 + r;
        float msk0 = (1.0f - (float)(amn0 * amm[r])) * INFV;
        float msk1 = (1.0f - (float)(amn1 * amm[r])) * INFV;
        pen0[r] = msk0 + ((n0 < m) ? INFV : 0.0f);
        pen1[r] = msk1 + ((n0 + 1 < m) ? INFV : 0.0f);
        bool b0 = (amn0 * amm[r] != 1) || (n0 < m);
        bool b1m = (amn1 * amm[r] != 1) || (n0 + 1 < m);
        mo[r].x = b0 ? 1.0f : 0.0f;
        mo[r].y = b1m ? 1.0f : 0.0f;
    }

    float2 be[HEADS];
#pragma unroll
    for (int h = 0; h < HEADS; ++h) {
        size_t ix = (size_t)(b * N2 + 2 * h) * SEQ + n0;
        float2 e0 = *(const float2*)&bP0[ix];
        float2 e1 = *(const float2*)&bP1[ix];
        be[h] = make_float2(e0.x + e1.x, e0.y + e1.y);
    }

    const size_t obase = (size_t)b * HEADS * SEQ * SEQ + n0;
#pragma unroll
    for (int h = 0; h < HEADS; ++h) {
#pragma unroll
        for (int r = 0; r < 8; ++r) {
            float2 v;
            v.x = fmaf(qk0[r], 0.125f, be[h].x + bo[r][h]) - pen0[r];
            v.y = fmaf(qk1[r], 0.125f, be[h].y + bo[r][h]) - pen1[r];
            *(float2*)&out[obase + ((size_t)h * SEQ + m0 + r) * SEQ] = v;
        }
    }
    const size_t mbase = (size_t)BSZ * HEADS * SEQ * SEQ
                       + ((size_t)b * SEQ + m0) * SEQ + n0;
#pragma unroll
    for (int r = 0; r < 8; ++r)
        *(float2*)&out[mbase + (size_t)r * SEQ] = mo[r];
}

extern "C" void kernel_launch(void* const* d_in, const int* in_sizes, int n_in,
                              void* d_out, int out_size, void* d_ws, size_t ws_size,
                              hipStream_t stream) {
    const float* inp = (const float*)d_in[0];
    const int*   am  = (const int*)d_in[1];
    const float* W1  = (const float*)d_in[2];
    const float* b1  = (const float*)d_in[3];
    const float* W2  = (const float*)d_in[4];
    const float* b2  = (const float*)d_in[5];

    float* ws    = (float*)d_ws;
    float* qw    = ws;                              // 262144 floats
    float* kwT   = ws + 262144;                     // 262144 floats
    float* bP0   = ws + 524288;                     //  98304 floats
    float* bP1   = ws + 622592;                     //  98304 floats
    unsigned short* W1T = (unsigned short*)(ws + 720896);   // 98304 bf16 slots (192 KB)
    float* W2T   = ws + 819200;                     //   3072 floats
    float2* sct  = (float2*)(ws + 822272);          //  16384 float2 (128 KB)

    float* out = (float*)d_out;

    hipLaunchKernelGGL(k0_prep, dim3(129), dim3(128), 0, stream,
                       W1, W2, W1T, W2T, sct);
    hipLaunchKernelGGL(k1_proj, dim3(512), dim3(512), 0, stream,
                       inp, W1T, b1, W2T, b2, sct, qw, kwT, bP0, bP1);
    hipLaunchKernelGGL(k2_out, dim3(4096 / 8), dim3(256), 0, stream,
                       qw, kwT, bP0, bP1, am, out);
}

// Round 7
// 40.103 us; speedup vs baseline: 1.2429x; 1.2429x over previous
//
#include <hip/hip_runtime.h>

#define BSZ 8
#define SEQ 512
#define HID 768
#define N1 128
#define N2 24
#define HS 64
#define HEADS 12
#define INFV 10000.0f

typedef __attribute__((ext_vector_type(8))) short s8b;     // 8 bf16 (4 VGPR)
typedef __attribute__((ext_vector_type(4))) float f32x4;   // MFMA acc

__device__ __forceinline__ unsigned short f2bf(float f) {
    union { float f; unsigned int u; } c; c.f = f;
    unsigned int u = c.u;
    u += 0x7FFFu + ((u >> 16) & 1u);   // RNE
    return (unsigned short)(u >> 16);
}

// Build bf16 B-fragment from W1 column cg, 8 consecutive k (stride N1 floats).
__device__ __forceinline__ s8b loadB(const float* __restrict__ wsrc) {
    union { s8b v; unsigned short u[8]; } r;
#pragma unroll
    for (int i = 0; i < 8; ++i) r.u[i] = f2bf(wsrc[i * N1]);
    return r.v;
}

// A-fragment slot (XOR-swizzled): chunk = global k/8, row = lr
#define ASLOT(chunk, r) (((chunk) * 16 + ((r) ^ ((chunk) & 7))) * 8)

// k1: 512 blocks x 512 thr. Block = 16 rows x 64 cols (col-half ch = bid&1).
// 8 waves = 4 col-tiles x 2 K-halves; bf16 MFMA; A staged in swizzled LDS,
// B converted in-register from W1. Epilogue: native-sincos RoPE -> qw + kwT,
// bias partial (x_half @ W2) -> bP[ch].
__global__ __launch_bounds__(512, 4) void k1_proj(
    const float* __restrict__ inp, const float* __restrict__ W1,
    const float* __restrict__ b1, const float* __restrict__ W2,
    const float* __restrict__ b2,
    float* __restrict__ qw, float* __restrict__ kwT,
    float* __restrict__ bP0, float* __restrict__ bP1)
{
    __shared__ unsigned short aF[96 * 16 * 8];   // 24 KB, XOR-swizzled slots
    __shared__ float ps[16][64];                 // K-half-1 partials
    __shared__ float xs[16][72];                 // x tile (row stride 288B)
    __shared__ float kT[32][17];                 // kwT transpose staging

    const int tid = threadIdx.x;
    const int rt = blockIdx.x >> 1;
    const int ch = blockIdx.x & 1;               // col half
    const int row0 = rt * 16;
    const int b = row0 >> 9;
    const int m0 = row0 & 511;

    {   // stage inp (fp32 -> bf16 swizzled fragment layout)
        const float4* src = (const float4*)(inp + (size_t)row0 * HID);
#pragma unroll
        for (int i = 0; i < 6; ++i) {
            int f4 = tid + i * 512;        // 0..3071
            int r = f4 / 192;              // row 0..15
            int c4 = f4 % 192;             // float4 idx in row; k = c4*4
            float4 v = src[f4];
            int chunk = c4 >> 1;
            int half = c4 & 1;
            ushort4 w;
            w.x = f2bf(v.x); w.y = f2bf(v.y); w.z = f2bf(v.z); w.w = f2bf(v.w);
            *(ushort4*)&aF[ASLOT(chunk, r) + half * 4] = w;
        }
    }
    __syncthreads();

    const int wv = tid >> 6;
    const int ln = tid & 63;
    const int lr = ln & 15;        // A row / B col within tile
    const int lg = ln >> 4;        // k-group
    const int w3 = wv & 3;         // col tile
    const int kh = wv >> 2;        // K half
    const int cg = ch * 64 + w3 * 16 + lr;   // global x-col

    // B source: W1[k][cg], k = kh*384 + kc*32 + lg*8 + i
    const float* wbase = W1 + (size_t)(kh * 384 + lg * 8) * N1 + cg;

    f32x4 acc = {0.f, 0.f, 0.f, 0.f};
    s8b bA = loadB(wbase);
    s8b bB = loadB(wbase + 32 * N1);

#define AFRAG(kc) (*(const s8b*)&aF[ASLOT((kh * 12 + (kc)) * 4 + lg, lr)])
#pragma unroll
    for (int kc = 0; kc < 12; kc += 2) {
        acc = __builtin_amdgcn_mfma_f32_16x16x32_bf16(AFRAG(kc), bA, acc, 0, 0, 0);
        if (kc + 2 < 12) bA = loadB(wbase + (size_t)(kc + 2) * 32 * N1);
        acc = __builtin_amdgcn_mfma_f32_16x16x32_bf16(AFRAG(kc + 1), bB, acc, 0, 0, 0);
        if (kc + 3 < 12) bB = loadB(wbase + (size_t)(kc + 3) * 32 * N1);
    }
#undef AFRAG

    if (kh == 1) {   // upper-K partials -> LDS
#pragma unroll
        for (int g = 0; g < 4; ++g) ps[lg * 4 + g][w3 * 16 + lr] = acc[g];
    }
    __syncthreads();
    if (kh == 0) {   // merge + b1 -> xs (local col = w3*16+lr)
        float b1v = b1[cg];
#pragma unroll
        for (int g = 0; g < 4; ++g)
            xs[lg * 4 + g][w3 * 16 + lr] = acc[g] + ps[lg * 4 + g][w3 * 16 + lr] + b1v;
    }
    __syncthreads();

    // bias partial: bP[ch][(b,c,m)] = (x_half . W2[half,c] [+ b2 if ch==0]) * 0.5
    if (tid < 16 * N2) {
        int r = tid / N2, c = tid - r * N2;
        const float* w2p = W2 + (size_t)(ch * 64) * N2 + c;
        float dot = (ch == 0) ? b2[c] : 0.0f;
#pragma unroll 8
        for (int kl = 0; kl < 64; ++kl)
            dot = fmaf(xs[r][kl], w2p[kl * N2], dot);
        float* bP = ch ? bP1 : bP0;
        bP[(size_t)(b * N2 + c) * SEQ + m0 + r] = dot * 0.5f;
    }

    if (tid < 256) {   // RoPE: 16 rows x 16 local pairs (j = ch*16 + jj)
        const int r = tid >> 4, jj = tid & 15;
        const int j = ch * 16 + jj;
        const int m = m0 + r;
        const float C = 0.4152410118609203f;      // log2(10000)/32
        float invf = exp2f(-(float)j * C);        // 10000^(-j/32)
        float ang = (float)m * invf;
        float sv = __sinf(ang), cv = __cosf(ang);
        float4 xv = *(const float4*)&xs[r][4 * jj];
        float rq0 = xv.x * cv - xv.z * sv;        // q pair = x[4j], x[4j+2]
        float rq1 = xv.x * sv + xv.z * cv;
        float rk0 = xv.y * cv - xv.w * sv;        // k pair = x[4j+1], x[4j+3]
        float rk1 = xv.y * sv + xv.w * cv;
        *(float2*)(qw + (size_t)(b * SEQ + m) * HS + 2 * j) = make_float2(rq0, rq1);
        kT[2 * jj][r]     = rk0;
        kT[2 * jj + 1][r] = rk1;
    }
    __syncthreads();

    if (tid < 256) {   // kwT writeout: 32 local d-rows x 8 m-pairs
        int dl = tid >> 3, q = tid & 7;
        float2 v = *(const float2*)&kT[dl][2 * q];
        *(float2*)(kwT + (size_t)(b * HS + ch * 32 + dl) * SEQ + m0 + 2 * q) = v;
    }
}

// k2: per block = (b, 8 m-rows) x 512 n. 256 threads, 2 n's each -> float2 stores.
__global__ __launch_bounds__(256) void k2_out(
    const float* __restrict__ qw, const float* __restrict__ kwT,
    const float* __restrict__ bP0, const float* __restrict__ bP1,
    const int* __restrict__ am, float* __restrict__ out)
{
    __shared__ float q_lds[8][HS];
    __shared__ float bo[8][HEADS];
    __shared__ int amm[8];

    const int tid = threadIdx.x;
    const int b = blockIdx.x >> 6;
    const int m0 = (blockIdx.x & 63) * 8;

#pragma unroll
    for (int i = 0; i < 2; ++i) {
        int idx = tid + i * 256;
        q_lds[idx >> 6][idx & 63] = qw[(size_t)(b * SEQ + m0) * HS + idx];
    }
    if (tid < 96) {
        int r = tid / 12, h = tid - r * 12;
        size_t ix = (size_t)(b * N2 + 2 * h + 1) * SEQ + m0 + r;
        bo[r][h] = bP0[ix] + bP1[ix];
    }
    if (tid < 8) amm[tid] = am[b * SEQ + m0 + tid];
    __syncthreads();

    const int n0 = tid * 2;
    float qk0[8] = {0, 0, 0, 0, 0, 0, 0, 0};
    float qk1[8] = {0, 0, 0, 0, 0, 0, 0, 0};

#pragma unroll
    for (int dc = 0; dc < 2; ++dc) {
        float2 kn[32];
#pragma unroll
        for (int d = 0; d < 32; ++d)
            kn[d] = *(const float2*)&kwT[(size_t)(b * HS + dc * 32 + d) * SEQ + n0];
#pragma unroll
        for (int r = 0; r < 8; ++r) {
#pragma unroll
            for (int d4 = 0; d4 < 8; ++d4) {
                float4 qv = *(const float4*)&q_lds[r][dc * 32 + d4 * 4];
                qk0[r] = fmaf(qv.x, kn[d4 * 4 + 0].x, qk0[r]);
                qk0[r] = fmaf(qv.y, kn[d4 * 4 + 1].x, qk0[r]);
                qk0[r] = fmaf(qv.z, kn[d4 * 4 + 2].x, qk0[r]);
                qk0[r] = fmaf(qv.w, kn[d4 * 4 + 3].x, qk0[r]);
                qk1[r] = fmaf(qv.x, kn[d4 * 4 + 0].y, qk1[r]);
                qk1[r] = fmaf(qv.y, kn[d4 * 4 + 1].y, qk1[r]);
                qk1[r] = fmaf(qv.z, kn[d4 * 4 + 2].y, qk1[r]);
                qk1[r] = fmaf(qv.w, kn[d4 * 4 + 3].y, qk1[r]);
            }
        }
    }

    const int amn0 = am[b * SEQ + n0];
    const int amn1 = am[b * SEQ + n0 + 1];
    float pen0[8], pen1[8];
    float2 mo[8];
#pragma unroll
    for (int r = 0; r < 8; ++r) {
        int m = m0 + r;
        float msk0 = (1.0f - (float)(amn0 * amm[r])) * INFV;
        float msk1 = (1.0f - (float)(amn1 * amm[r])) * INFV;
        pen0[r] = msk0 + ((n0 < m) ? INFV : 0.0f);
        pen1[r] = msk1 + ((n0 + 1 < m) ? INFV : 0.0f);
        bool b0 = (amn0 * amm[r] != 1) || (n0 < m);
        bool b1m = (amn1 * amm[r] != 1) || (n0 + 1 < m);
        mo[r].x = b0 ? 1.0f : 0.0f;
        mo[r].y = b1m ? 1.0f : 0.0f;
    }

    float2 be[HEADS];
#pragma unroll
    for (int h = 0; h < HEADS; ++h) {
        size_t ix = (size_t)(b * N2 + 2 * h) * SEQ + n0;
        float2 e0 = *(const float2*)&bP0[ix];
        float2 e1 = *(const float2*)&bP1[ix];
        be[h] = make_float2(e0.x + e1.x, e0.y + e1.y);
    }

    const size_t obase = (size_t)b * HEADS * SEQ * SEQ + n0;
#pragma unroll
    for (int h = 0; h < HEADS; ++h) {
#pragma unroll
        for (int r = 0; r < 8; ++r) {
            float2 v;
            v.x = fmaf(qk0[r], 0.125f, be[h].x + bo[r][h]) - pen0[r];
            v.y = fmaf(qk1[r], 0.125f, be[h].y + bo[r][h]) - pen1[r];
            *(float2*)&out[obase + ((size_t)h * SEQ + m0 + r) * SEQ] = v;
        }
    }
    const size_t mbase = (size_t)BSZ * HEADS * SEQ * SEQ
                       + ((size_t)b * SEQ + m0) * SEQ + n0;
#pragma unroll
    for (int r = 0; r < 8; ++r)
        *(float2*)&out[mbase + (size_t)r * SEQ] = mo[r];
}

extern "C" void kernel_launch(void* const* d_in, const int* in_sizes, int n_in,
                              void* d_out, int out_size, void* d_ws, size_t ws_size,
                              hipStream_t stream) {
    const float* inp = (const float*)d_in[0];
    const int*   am  = (const int*)d_in[1];
    const float* W1  = (const float*)d_in[2];
    const float* b1  = (const float*)d_in[3];
    const float* W2  = (const float*)d_in[4];
    const float* b2  = (const float*)d_in[5];

    float* ws    = (float*)d_ws;
    float* qw    = ws;                              // 262144 floats
    float* kwT   = ws + 262144;                     // 262144 floats
    float* bP0   = ws + 524288;                     //  98304 floats
    float* bP1   = ws + 622592;                     //  98304 floats

    float* out = (float*)d_out;

    hipLaunchKernelGGL(k1_proj, dim3(512), dim3(512), 0, stream,
                       inp, W1, b1, W2, b2, qw, kwT, bP0, bP1);
    hipLaunchKernelGGL(k2_out, dim3(4096 / 8), dim3(256), 0, stream,
                       qw, kwT, bP0, bP1, am, out);
}